// Round 2
// baseline (53478.412 us; speedup 1.0000x reference)
//
#include <hip/hip_runtime.h>

// LSTM 2-layer fused persistent kernel, full fp32.
// 256 workgroups (1 per batch row / CU), 1024 threads: thread = (row g of
// 4H=512, half of K). Per-thread live weights <= 16 float4 (64 VGPR) so
// everything stays register-resident under the hard 128-VGPR cap at 16 waves.
// Per chunk of TC=32 steps:
//   A: stage x chunk to LDS (+carry h0)
//   B: xp0[t][g] = bias0 + Wih0[g,:].x_t     (batched mini-GEMM, K=64)
//   C: layer0 serial: gates = xp0 + Whh0.h0  (16 ds_read_b128 + 64 FMA/thr)
//   D: xp1[t][g] = bias1 + Wih1[g,:].h0_t    (batched mini-GEMM, K=128)
//   E: layer1 serial: gates = xp1 + Whh1.h1
// xp0/xp1 share one 64KB LDS buffer. Weights reload per chunk from L2 (hot).

#define NB   256
#define TSEQ 1024
#define II   64
#define HH   128
#define G4   512
#define TC   32
#define NCH  (TSEQ/TC)

__device__ __forceinline__ float sigm(float x){ return 1.f/(1.f+__expf(-x)); }
__device__ __forceinline__ float tanh_f(float x){
    float ax = fabsf(x);
    float e  = __expf(2.f*ax);
    float t  = 1.f - 2.f/(e + 1.f);
    return copysignf(t, x);
}

__global__ __launch_bounds__(1024, 4)
void lstm_all(const float* __restrict__ x,
              const float* __restrict__ Wih0, const float* __restrict__ Whh0,
              const float* __restrict__ bih0, const float* __restrict__ bhh0,
              const float* __restrict__ Wih1, const float* __restrict__ Whh1,
              const float* __restrict__ bih1, const float* __restrict__ bhh1,
              const float* __restrict__ Wlin, const float* __restrict__ blin,
              float* __restrict__ out)
{
    const int b    = blockIdx.x;
    const int tid  = threadIdx.x;
    const int row  = tid >> 1;    // gate row 0..511
    const int half = tid & 1;     // K-half

    __shared__ __align__(16) float xp[TC][G4];        // 65,536 B (xp0 then xp1)
    __shared__ __align__(16) float h0buf[TC+1][HH];   // 16,896 B
    __shared__ __align__(16) float xc[TC][II];        //  8,192 B
    __shared__ __align__(16) float gates[G4];         //  2,048 B
    __shared__ __align__(16) float h1buf[HH];         //    512 B
    // total ~93 KB

    float c0 = 0.f, c1 = 0.f;     // cell state, owned by tid<128
    const float bias0 = bih0[row] + bhh0[row];
    const float bias1 = bih1[row] + bhh1[row];
    const bool  tanh_gate = (row >= 2*HH) && (row < 3*HH);  // wave-uniform

    if (tid < HH) { h0buf[0][tid] = 0.f; h1buf[tid] = 0.f; }

    const float* xb = x + (size_t)b * TSEQ * II;

    for (int ch = 0; ch < NCH; ++ch) {
        // ---------- Phase A: stage x chunk, carry h0 ----------
        if (tid < 512) {
            ((float4*)&xc[0][0])[tid] =
                ((const float4*)(xb + (size_t)ch * TC * II))[tid];
        }
        if (ch > 0 && tid < HH) h0buf[0][tid] = h0buf[TC][tid];
        __syncthreads();

        // ---------- Phase B: xp0 = bias0 + Wih0 . x  (K half = 32) ----------
        {
            float4 w[8];
            const float4* wp = (const float4*)(Wih0 + (size_t)row*II + half*(II/2));
            #pragma unroll
            for (int i = 0; i < 8; ++i) w[i] = wp[i];
            #pragma unroll
            for (int sub = 0; sub < TC/8; ++sub) {
                float acc[8];
                #pragma unroll
                for (int i = 0; i < 8; ++i) acc[i] = 0.f;
                #pragma unroll
                for (int k4 = 0; k4 < 8; ++k4) {
                    #pragma unroll
                    for (int tt = 0; tt < 8; ++tt) {
                        float4 v = *(const float4*)&xc[sub*8+tt][half*(II/2) + k4*4];
                        acc[tt] += w[k4].x*v.x + w[k4].y*v.y + w[k4].z*v.z + w[k4].w*v.w;
                    }
                }
                #pragma unroll
                for (int tt = 0; tt < 8; ++tt) {
                    float s = acc[tt] + __shfl_xor(acc[tt], 1);
                    if (half == 0) xp[sub*8+tt][row] = s + bias0;
                }
            }
        }
        __syncthreads();

        // ---------- Phase C: layer0 serial (K half = 64) ----------
        {
            float4 wh[16];
            const float4* wp = (const float4*)(Whh0 + (size_t)row*HH + half*(HH/2));
            #pragma unroll
            for (int i = 0; i < 16; ++i) wh[i] = wp[i];
            #pragma unroll 1
            for (int t = 0; t < TC; ++t) {
                float a0=0.f, a1=0.f, a2=0.f, a3=0.f;
                #pragma unroll
                for (int k4 = 0; k4 < 16; ++k4) {
                    float4 v = *(const float4*)&h0buf[t][half*(HH/2) + k4*4];
                    a0 += wh[k4].x*v.x; a1 += wh[k4].y*v.y;
                    a2 += wh[k4].z*v.z; a3 += wh[k4].w*v.w;
                }
                float s = (a0+a1)+(a2+a3);
                s += __shfl_xor(s, 1);
                if (half == 0) {
                    float pre = xp[t][row] + s;
                    gates[row] = tanh_gate ? tanh_f(pre) : sigm(pre);
                }
                __syncthreads();
                if (tid < HH) {
                    float iv = gates[tid],        fv = gates[HH + tid];
                    float gv = gates[2*HH + tid], ov = gates[3*HH + tid];
                    c0 = fv*c0 + iv*gv;
                    h0buf[t+1][tid] = ov * tanh_f(c0);
                }
                __syncthreads();
            }
        }

        // ---------- Phase D: xp1 = bias1 + Wih1 . h0  (K half = 64) ----------
        {
            float4 w[16];
            const float4* wp = (const float4*)(Wih1 + (size_t)row*HH + half*(HH/2));
            #pragma unroll
            for (int i = 0; i < 16; ++i) w[i] = wp[i];
            #pragma unroll
            for (int sub = 0; sub < TC/8; ++sub) {
                float acc[8];
                #pragma unroll
                for (int i = 0; i < 8; ++i) acc[i] = 0.f;
                #pragma unroll
                for (int k4 = 0; k4 < 16; ++k4) {
                    #pragma unroll
                    for (int tt = 0; tt < 8; ++tt) {
                        float4 v = *(const float4*)&h0buf[sub*8+tt+1][half*(HH/2) + k4*4];
                        acc[tt] += w[k4].x*v.x + w[k4].y*v.y + w[k4].z*v.z + w[k4].w*v.w;
                    }
                }
                #pragma unroll
                for (int tt = 0; tt < 8; ++tt) {
                    float s = acc[tt] + __shfl_xor(acc[tt], 1);
                    if (half == 0) xp[sub*8+tt][row] = s + bias1;
                }
            }
        }
        __syncthreads();

        // ---------- Phase E: layer1 serial (K half = 64) ----------
        {
            float4 wh[16];
            const float4* wp = (const float4*)(Whh1 + (size_t)row*HH + half*(HH/2));
            #pragma unroll
            for (int i = 0; i < 16; ++i) wh[i] = wp[i];
            #pragma unroll 1
            for (int t = 0; t < TC; ++t) {
                float a0=0.f, a1=0.f, a2=0.f, a3=0.f;
                #pragma unroll
                for (int k4 = 0; k4 < 16; ++k4) {
                    float4 v = *(const float4*)&h1buf[half*(HH/2) + k4*4];
                    a0 += wh[k4].x*v.x; a1 += wh[k4].y*v.y;
                    a2 += wh[k4].z*v.z; a3 += wh[k4].w*v.w;
                }
                float s = (a0+a1)+(a2+a3);
                s += __shfl_xor(s, 1);
                if (half == 0) {
                    float pre = xp[t][row] + s;
                    gates[row] = tanh_gate ? tanh_f(pre) : sigm(pre);
                }
                __syncthreads();
                if (tid < HH) {
                    float iv = gates[tid],        fv = gates[HH + tid];
                    float gv = gates[2*HH + tid], ov = gates[3*HH + tid];
                    c1 = fv*c1 + iv*gv;
                    h1buf[tid] = ov * tanh_f(c1);
                }
                __syncthreads();
            }
        }
    }

    // ---------- final linear: out[b] = h1 . Wlin[0,:] + blin ----------
    if (tid < 64) {
        float s = h1buf[tid]*Wlin[tid] + h1buf[tid+64]*Wlin[tid+64];
        #pragma unroll
        for (int off = 32; off; off >>= 1) s += __shfl_down(s, off);
        if (tid == 0) out[b] = s + blin[0];
    }
}

extern "C" void kernel_launch(void* const* d_in, const int* in_sizes, int n_in,
                              void* d_out, int out_size, void* d_ws, size_t ws_size,
                              hipStream_t stream)
{
    const float* x    = (const float*)d_in[0];
    const float* Wih0 = (const float*)d_in[1];
    const float* Whh0 = (const float*)d_in[2];
    const float* bih0 = (const float*)d_in[3];
    const float* bhh0 = (const float*)d_in[4];
    const float* Wih1 = (const float*)d_in[5];
    const float* Whh1 = (const float*)d_in[6];
    const float* bih1 = (const float*)d_in[7];
    const float* bhh1 = (const float*)d_in[8];
    const float* Wlin = (const float*)d_in[9];
    const float* blin = (const float*)d_in[10];
    float* out = (float*)d_out;

    hipLaunchKernelGGL(lstm_all, dim3(NB), dim3(1024), 0, stream,
                       x, Wih0, Whh0, bih0, bhh0,
                       Wih1, Whh1, bih1, bhh1, Wlin, blin, out);
}

// Round 3
// 31703.619 us; speedup vs baseline: 1.6868x; 1.6868x over previous
//
#include <hip/hip_runtime.h>

// LSTM 2-layer fused persistent kernel, full fp32.
// 256 workgroups (1 per batch row / CU), 1024 threads: thread = (row g of
// 4H=512, half of K). Per-thread live weights <= 16 float4 (64 VGPR).
// __launch_bounds__(1024, 1): second arg is min BLOCKS/CU (CUDA semantics,
// verified R1/R2: (512,2)->128 VGPR, (1024,4)->64 VGPR+spill). 1 block/CU
// -> 128-VGPR cap, weights fit register-resident.
// KEEP4 empty-asm pins loaded weights: no remat (R1, 30GB refetch), no
// spill-friendly liveness games (R2, 58GB scratch writes).
// Per chunk of TC=32 steps:
//   A: stage x chunk to LDS (+carry h0)
//   B: xp0[t][g] = bias0 + Wih0[g,:].x_t     (batched mini-GEMM, K=64)
//   C: layer0 serial: gates = xp0 + Whh0.h0  (16 ds_read_b128 + 64 FMA/thr)
//   D: xp1[t][g] = bias1 + Wih1[g,:].h0_t    (batched mini-GEMM, K=128)
//   E: layer1 serial: gates = xp1 + Whh1.h1

#define NB   256
#define TSEQ 1024
#define II   64
#define HH   128
#define G4   512
#define TC   32
#define NCH  (TSEQ/TC)

#define KEEP4(v) asm volatile("" : "+v"((v).x), "+v"((v).y), "+v"((v).z), "+v"((v).w))

__device__ __forceinline__ float sigm(float x){ return 1.f/(1.f+__expf(-x)); }
__device__ __forceinline__ float tanh_f(float x){
    float ax = fabsf(x);
    float e  = __expf(2.f*ax);
    float t  = 1.f - 2.f/(e + 1.f);
    return copysignf(t, x);
}

__global__ __launch_bounds__(1024, 1)
void lstm_all(const float* __restrict__ x,
              const float* __restrict__ Wih0, const float* __restrict__ Whh0,
              const float* __restrict__ bih0, const float* __restrict__ bhh0,
              const float* __restrict__ Wih1, const float* __restrict__ Whh1,
              const float* __restrict__ bih1, const float* __restrict__ bhh1,
              const float* __restrict__ Wlin, const float* __restrict__ blin,
              float* __restrict__ out)
{
    const int b    = blockIdx.x;
    const int tid  = threadIdx.x;
    const int row  = tid >> 1;    // gate row 0..511
    const int half = tid & 1;     // K-half

    __shared__ __align__(16) float xp[TC][G4];        // 65,536 B (xp0 then xp1)
    __shared__ __align__(16) float h0buf[TC+1][HH];   // 16,896 B
    __shared__ __align__(16) float xc[TC][II];        //  8,192 B
    __shared__ __align__(16) float gates[G4];         //  2,048 B
    __shared__ __align__(16) float h1buf[HH];         //    512 B
    // total ~93 KB -> 1 block/CU

    float c0 = 0.f, c1 = 0.f;     // cell state, owned by tid<128
    const float bias0 = bih0[row] + bhh0[row];
    const float bias1 = bih1[row] + bhh1[row];
    const bool  tanh_gate = (row >= 2*HH) && (row < 3*HH);  // wave-uniform

    if (tid < HH) { h0buf[0][tid] = 0.f; h1buf[tid] = 0.f; }

    const float* xb = x + (size_t)b * TSEQ * II;

    for (int ch = 0; ch < NCH; ++ch) {
        // ---------- Phase A: stage x chunk, carry h0 ----------
        if (tid < 512) {
            ((float4*)&xc[0][0])[tid] =
                ((const float4*)(xb + (size_t)ch * TC * II))[tid];
        }
        if (ch > 0 && tid < HH) h0buf[0][tid] = h0buf[TC][tid];
        __syncthreads();

        // ---------- Phase B: xp0 = bias0 + Wih0 . x  (K half = 32) ----------
        {
            float4 w[8];
            const float4* wp = (const float4*)(Wih0 + (size_t)row*II + half*(II/2));
            #pragma unroll
            for (int i = 0; i < 8; ++i) w[i] = wp[i];
            #pragma unroll
            for (int i = 0; i < 8; ++i) KEEP4(w[i]);
            #pragma unroll
            for (int sub = 0; sub < TC/8; ++sub) {
                float acc[8];
                #pragma unroll
                for (int i = 0; i < 8; ++i) acc[i] = 0.f;
                #pragma unroll
                for (int k4 = 0; k4 < 8; ++k4) {
                    #pragma unroll
                    for (int tt = 0; tt < 8; ++tt) {
                        float4 v = *(const float4*)&xc[sub*8+tt][half*(II/2) + k4*4];
                        acc[tt] += w[k4].x*v.x + w[k4].y*v.y + w[k4].z*v.z + w[k4].w*v.w;
                    }
                }
                #pragma unroll
                for (int tt = 0; tt < 8; ++tt) {
                    float s = acc[tt] + __shfl_xor(acc[tt], 1);
                    if (half == 0) xp[sub*8+tt][row] = s + bias0;
                }
            }
        }
        __syncthreads();

        // ---------- Phase C: layer0 serial (K half = 64) ----------
        {
            float4 wh[16];
            const float4* wp = (const float4*)(Whh0 + (size_t)row*HH + half*(HH/2));
            #pragma unroll
            for (int i = 0; i < 16; ++i) wh[i] = wp[i];
            #pragma unroll
            for (int i = 0; i < 16; ++i) KEEP4(wh[i]);
            #pragma unroll 1
            for (int t = 0; t < TC; ++t) {
                float a0=0.f, a1=0.f, a2=0.f, a3=0.f;
                #pragma unroll
                for (int k4 = 0; k4 < 16; ++k4) {
                    float4 v = *(const float4*)&h0buf[t][half*(HH/2) + k4*4];
                    a0 += wh[k4].x*v.x; a1 += wh[k4].y*v.y;
                    a2 += wh[k4].z*v.z; a3 += wh[k4].w*v.w;
                }
                float s = (a0+a1)+(a2+a3);
                s += __shfl_xor(s, 1);
                if (half == 0) {
                    float pre = xp[t][row] + s;
                    gates[row] = tanh_gate ? tanh_f(pre) : sigm(pre);
                }
                __syncthreads();
                if (tid < HH) {
                    float iv = gates[tid],        fv = gates[HH + tid];
                    float gv = gates[2*HH + tid], ov = gates[3*HH + tid];
                    c0 = fv*c0 + iv*gv;
                    h0buf[t+1][tid] = ov * tanh_f(c0);
                }
                __syncthreads();
            }
        }

        // ---------- Phase D: xp1 = bias1 + Wih1 . h0  (K half = 64) ----------
        {
            float4 w[16];
            const float4* wp = (const float4*)(Wih1 + (size_t)row*HH + half*(HH/2));
            #pragma unroll
            for (int i = 0; i < 16; ++i) w[i] = wp[i];
            #pragma unroll
            for (int i = 0; i < 16; ++i) KEEP4(w[i]);
            #pragma unroll
            for (int sub = 0; sub < TC/8; ++sub) {
                float acc[8];
                #pragma unroll
                for (int i = 0; i < 8; ++i) acc[i] = 0.f;
                #pragma unroll
                for (int k4 = 0; k4 < 16; ++k4) {
                    #pragma unroll
                    for (int tt = 0; tt < 8; ++tt) {
                        float4 v = *(const float4*)&h0buf[sub*8+tt+1][half*(HH/2) + k4*4];
                        acc[tt] += w[k4].x*v.x + w[k4].y*v.y + w[k4].z*v.z + w[k4].w*v.w;
                    }
                }
                #pragma unroll
                for (int tt = 0; tt < 8; ++tt) {
                    float s = acc[tt] + __shfl_xor(acc[tt], 1);
                    if (half == 0) xp[sub*8+tt][row] = s + bias1;
                }
            }
        }
        __syncthreads();

        // ---------- Phase E: layer1 serial (K half = 64) ----------
        {
            float4 wh[16];
            const float4* wp = (const float4*)(Whh1 + (size_t)row*HH + half*(HH/2));
            #pragma unroll
            for (int i = 0; i < 16; ++i) wh[i] = wp[i];
            #pragma unroll
            for (int i = 0; i < 16; ++i) KEEP4(wh[i]);
            #pragma unroll 1
            for (int t = 0; t < TC; ++t) {
                float a0=0.f, a1=0.f, a2=0.f, a3=0.f;
                #pragma unroll
                for (int k4 = 0; k4 < 16; ++k4) {
                    float4 v = *(const float4*)&h1buf[half*(HH/2) + k4*4];
                    a0 += wh[k4].x*v.x; a1 += wh[k4].y*v.y;
                    a2 += wh[k4].z*v.z; a3 += wh[k4].w*v.w;
                }
                float s = (a0+a1)+(a2+a3);
                s += __shfl_xor(s, 1);
                if (half == 0) {
                    float pre = xp[t][row] + s;
                    gates[row] = tanh_gate ? tanh_f(pre) : sigm(pre);
                }
                __syncthreads();
                if (tid < HH) {
                    float iv = gates[tid],        fv = gates[HH + tid];
                    float gv = gates[2*HH + tid], ov = gates[3*HH + tid];
                    c1 = fv*c1 + iv*gv;
                    h1buf[tid] = ov * tanh_f(c1);
                }
                __syncthreads();
            }
        }
    }

    // ---------- final linear: out[b] = h1 . Wlin[0,:] + blin ----------
    if (tid < 64) {
        float s = h1buf[tid]*Wlin[tid] + h1buf[tid+64]*Wlin[tid+64];
        #pragma unroll
        for (int off = 32; off; off >>= 1) s += __shfl_down(s, off);
        if (tid == 0) out[b] = s + blin[0];
    }
}

extern "C" void kernel_launch(void* const* d_in, const int* in_sizes, int n_in,
                              void* d_out, int out_size, void* d_ws, size_t ws_size,
                              hipStream_t stream)
{
    const float* x    = (const float*)d_in[0];
    const float* Wih0 = (const float*)d_in[1];
    const float* Whh0 = (const float*)d_in[2];
    const float* bih0 = (const float*)d_in[3];
    const float* bhh0 = (const float*)d_in[4];
    const float* Wih1 = (const float*)d_in[5];
    const float* Whh1 = (const float*)d_in[6];
    const float* bih1 = (const float*)d_in[7];
    const float* bhh1 = (const float*)d_in[8];
    const float* Wlin = (const float*)d_in[9];
    const float* blin = (const float*)d_in[10];
    float* out = (float*)d_out;

    hipLaunchKernelGGL(lstm_all, dim3(NB), dim3(1024), 0, stream,
                       x, Wih0, Whh0, bih0, bhh0,
                       Wih1, Whh1, bih1, bhh1, Wlin, blin, out);
}